// Round 1
// baseline (1544.726 us; speedup 1.0000x reference)
//
#include <hip/hip_runtime.h>
#include <hip/hip_bf16.h>
#include <stdint.h>

// Problem dims (fixed by reference)
#define M_DIM 8192    // B*S
#define N_DIM 11008   // OUT_F
#define K_DIM 4096    // IN_F

typedef __attribute__((ext_vector_type(8))) short short8;
typedef __attribute__((ext_vector_type(4))) float f32x4;

// round-to-nearest-even f32 -> bf16 bits (inputs finite)
__device__ __forceinline__ unsigned short f2bf(float f) {
  union { float f; unsigned int u; } c; c.f = f;
  unsigned int u = c.u;
  return (unsigned short)((u + 0x7fffu + ((u >> 16) & 1u)) >> 16);
}

// ---------------- pre-pass 1: x f32 -> bf16, 8 elems/thread ----------------
__global__ void cvt_x_kernel(const float* __restrict__ x,
                             unsigned short* __restrict__ xb) {
  int t = blockIdx.x * blockDim.x + threadIdx.x;
  const float4* xv = (const float4*)x + (size_t)t * 2;
  float4 v0 = xv[0], v1 = xv[1];
  union { unsigned short h[8]; uint4 u; } p;
  p.h[0] = f2bf(v0.x); p.h[1] = f2bf(v0.y); p.h[2] = f2bf(v0.z); p.h[3] = f2bf(v0.w);
  p.h[4] = f2bf(v1.x); p.h[5] = f2bf(v1.y); p.h[6] = f2bf(v1.z); p.h[7] = f2bf(v1.w);
  ((uint4*)xb)[t] = p.u;
}

// ---------------- pre-pass 2: dequant weights -> bf16 ----------------
// w[o][i] = sign>0 ? +sp[g] : -sn[g], g = (o*K + i)/128. 8 elems/thread.
__global__ void dequant_w_kernel(const float* __restrict__ signs,
                                 const float* __restrict__ sp,
                                 const float* __restrict__ sn,
                                 unsigned short* __restrict__ wb) {
  int t = blockIdx.x * blockDim.x + threadIdx.x;
  int g = t >> 4;                    // 16 threads per 128-elem group
  float spv = sp[g], snv = sn[g];
  const float4* sv = (const float4*)signs + (size_t)t * 2;
  float4 v0 = sv[0], v1 = sv[1];
  float f[8] = {v0.x, v0.y, v0.z, v0.w, v1.x, v1.y, v1.z, v1.w};
  union { unsigned short h[8]; uint4 u; } p;
#pragma unroll
  for (int j = 0; j < 8; ++j) p.h[j] = f2bf(f[j] > 0.f ? spv : -snv);
  ((uint4*)wb)[t] = p.u;
}

// ---------------- GEMM: C[M,N] = Xb[M,K] * Wb[N,K]^T (bf16 in, f32 out) ----
#define BM 128
#define BN 128
#define BK 32
#define NT (N_DIM / BN)                  // 86 tiles along N
#define NWG ((M_DIM / BM) * NT)          // 64*86 = 5504, % 8 == 0

__device__ __forceinline__ void gl_lds16(const void* g, void* l) {
  __builtin_amdgcn_global_load_lds(
      (const __attribute__((address_space(1))) unsigned int*)g,
      (__attribute__((address_space(3))) unsigned int*)l, 16, 0, 0);
}

__global__ __launch_bounds__(256, 2) void gemm_kernel(
    const unsigned short* __restrict__ A,   // [M,K] bf16 bits
    const unsigned short* __restrict__ Bm,  // [N,K] bf16 bits
    float* __restrict__ C) {
  __shared__ unsigned short As[BM][BK];
  __shared__ unsigned short Bs[BN][BK];

  // XCD-aware bijective swizzle (NWG % 8 == 0)
  int wg = blockIdx.x;
  const int cpx = NWG / 8;
  int swz = (wg & 7) * cpx + (wg >> 3);
  int tm = swz / NT, tn = swz % NT;
  int brow = tm * BM, bcol = tn * BN;

  int tid = threadIdx.x;
  int lane = tid & 63;
  int w = tid >> 6;                        // 4 waves as 2x2, each 64x64 out
  int wrow = (w >> 1) * 64, wcol = (w & 1) * 64;

  f32x4 acc[4][4];
#pragma unroll
  for (int i = 0; i < 4; ++i)
#pragma unroll
    for (int j = 0; j < 4; ++j) acc[i][j] = (f32x4){0.f, 0.f, 0.f, 0.f};

  const int frow = lane & 15;              // m/n index within fragment
  const int fko  = (lane >> 4) * 8;        // k octet within BK=32

  for (int kt = 0; kt < K_DIM / BK; ++kt) {
    int k0 = kt * BK;
    // stage A,B tiles: 128x32 bf16 = 8KB each = 512 x 16B; 2 chunks/thread ea.
#pragma unroll
    for (int i = 0; i < 2; ++i) {
      int c = i * 256 + tid;               // chunk id; lds dest = c*16 bytes
      int row = c >> 2, cq = c & 3;
      gl_lds16(A + (size_t)(brow + row) * K_DIM + k0 + cq * 8,
               &As[0][0] + c * 8);
      gl_lds16(Bm + (size_t)(bcol + row) * K_DIM + k0 + cq * 8,
               &Bs[0][0] + c * 8);
    }
    __syncthreads();                       // drains vmcnt before use

    short8 af[4], bf[4];
#pragma unroll
    for (int mi = 0; mi < 4; ++mi)
      af[mi] = *(const short8*)&As[wrow + mi * 16 + frow][fko];
#pragma unroll
    for (int ni = 0; ni < 4; ++ni)
      bf[ni] = *(const short8*)&Bs[wcol + ni * 16 + frow][fko];

#pragma unroll
    for (int mi = 0; mi < 4; ++mi)
#pragma unroll
      for (int ni = 0; ni < 4; ++ni)
        acc[mi][ni] = __builtin_amdgcn_mfma_f32_16x16x32_bf16(
            af[mi], bf[ni], acc[mi][ni], 0, 0, 0);
    __syncthreads();                       // before next overwrite
  }

  // epilogue: C/D layout col=lane&15, row=(lane>>4)*4+r  [m89/m91]
  int crow0 = brow + wrow + (lane >> 4) * 4;
  int ccol0 = bcol + wcol + (lane & 15);
#pragma unroll
  for (int mi = 0; mi < 4; ++mi)
#pragma unroll
    for (int ni = 0; ni < 4; ++ni) {
      int col = ccol0 + ni * 16;
      int rb = crow0 + mi * 16;
#pragma unroll
      for (int r = 0; r < 4; ++r)
        C[(size_t)(rb + r) * N_DIM + col] = acc[mi][ni][r];
    }
}

extern "C" void kernel_launch(void* const* d_in, const int* in_sizes, int n_in,
                              void* d_out, int out_size, void* d_ws, size_t ws_size,
                              hipStream_t stream) {
  const float* x     = (const float*)d_in[0];
  const float* signs = (const float*)d_in[1];
  const float* sp    = (const float*)d_in[2];
  const float* sn    = (const float*)d_in[3];
  float* out = (float*)d_out;

  // ws layout: xb (M*K bf16 = 64MiB) | wb (N*K bf16 = 86MiB); total ~150MiB
  unsigned short* xb = (unsigned short*)d_ws;
  unsigned short* wb = xb + (size_t)M_DIM * K_DIM;

  cvt_x_kernel<<<(M_DIM * K_DIM / 8) / 256, 256, 0, stream>>>(x, xb);
  dequant_w_kernel<<<((size_t)N_DIM * K_DIM / 8) / 256, 256, 0, stream>>>(signs, sp, sn, wb);
  gemm_kernel<<<NWG, 256, 0, stream>>>(xb, wb, out);
}

// Round 3
// 1219.549 us; speedup vs baseline: 1.2666x; 1.2666x over previous
//
#include <hip/hip_runtime.h>
#include <hip/hip_bf16.h>
#include <stdint.h>

// Problem dims (fixed by reference)
#define M_DIM 8192    // B*S
#define N_DIM 11008   // OUT_F
#define K_DIM 4096    // IN_F

typedef __attribute__((ext_vector_type(8))) short short8;
typedef __attribute__((ext_vector_type(4))) float f32x4;

// round-to-nearest-even f32 -> bf16 bits (inputs finite)
__device__ __forceinline__ unsigned short f2bf(float f) {
  union { float f; unsigned int u; } c; c.f = f;
  unsigned int u = c.u;
  return (unsigned short)((u + 0x7fffu + ((u >> 16) & 1u)) >> 16);
}

// ---------------- pre-pass 1: x f32 -> bf16, 8 elems/thread ----------------
__global__ void cvt_x_kernel(const float* __restrict__ x,
                             unsigned short* __restrict__ xb) {
  int t = blockIdx.x * blockDim.x + threadIdx.x;
  const float4* xv = (const float4*)x + (size_t)t * 2;
  float4 v0 = xv[0], v1 = xv[1];
  union { unsigned short h[8]; uint4 u; } p;
  p.h[0] = f2bf(v0.x); p.h[1] = f2bf(v0.y); p.h[2] = f2bf(v0.z); p.h[3] = f2bf(v0.w);
  p.h[4] = f2bf(v1.x); p.h[5] = f2bf(v1.y); p.h[6] = f2bf(v1.z); p.h[7] = f2bf(v1.w);
  ((uint4*)xb)[t] = p.u;
}

// ---------------- pre-pass 2: dequant weights -> bf16 ----------------
// w[o][i] = sign>0 ? +sp[g] : -sn[g], g = (o*K + i)/128. 8 elems/thread.
__global__ void dequant_w_kernel(const float* __restrict__ signs,
                                 const float* __restrict__ sp,
                                 const float* __restrict__ sn,
                                 unsigned short* __restrict__ wb) {
  int t = blockIdx.x * blockDim.x + threadIdx.x;
  int g = t >> 4;                    // 16 threads per 128-elem group
  float spv = sp[g], snv = sn[g];
  const float4* sv = (const float4*)signs + (size_t)t * 2;
  float4 v0 = sv[0], v1 = sv[1];
  float f[8] = {v0.x, v0.y, v0.z, v0.w, v1.x, v1.y, v1.z, v1.w};
  union { unsigned short h[8]; uint4 u; } p;
#pragma unroll
  for (int j = 0; j < 8; ++j) p.h[j] = f2bf(f[j] > 0.f ? spv : -snv);
  ((uint4*)wb)[t] = p.u;
}

// ================= GEMM: C[M,N] = Xb[M,K] * Wb[N,K]^T =====================
// 256x256 tile, BK=32, 512 threads (8 waves 2Mx4N), ring-4 LDS buffer,
// 2 phases per K-tile, counted vmcnt (T3+T4), XOR bank swizzle (T2),
// setprio around MFMA clusters (T5), XCD-aware block swizzle (T1).
#define BM 256
#define BN 256
#define BK 32
#define NT (N_DIM / BN)                 // 43
#define NWG ((M_DIM / BM) * NT)         // 32*43 = 1376, % 8 == 0
#define NK (K_DIM / BK)                 // 128 K-tiles

// LDS: A ring 4 x 16KB at 0, B ring 4 x 16KB at 64KB. 128 KiB total.
#define LDS_A(b) ((b) * 16384)
#define LDS_B(b) (65536 + (b) * 16384)

__device__ __forceinline__ void gl_lds16(const void* g, void* l) {
  __builtin_amdgcn_global_load_lds(
      (const __attribute__((address_space(1))) unsigned int*)g,
      (__attribute__((address_space(3))) unsigned int*)l, 16, 0, 0);
}

#define VM_WAIT(n) asm volatile("s_waitcnt vmcnt(" #n ")" ::: "memory")
#define BARRIER() do { __builtin_amdgcn_s_barrier(); asm volatile("" ::: "memory"); } while (0)

__global__ __launch_bounds__(512, 2) void gemm_kernel(
    const unsigned short* __restrict__ A,   // [M,K] bf16 bits
    const unsigned short* __restrict__ Bm,  // [N,K] bf16 bits
    float* __restrict__ C) {
  __shared__ __align__(16) unsigned char lds[131072];

  // T1: XCD-aware bijective swizzle (NWG % 8 == 0)
  int wg = blockIdx.x;
  const int cpx = NWG / 8;
  int swz = (wg & 7) * cpx + (wg >> 3);
  int tm = swz / NT, tn = swz % NT;
  const int brow = tm * BM, bcol = tn * BN;

  const int tid = threadIdx.x;
  const int lane = tid & 63;
  const int w = tid >> 6;
  const int wr = w >> 2;                 // 0..1: rows wr*128
  const int wc = w & 3;                  // 0..3: cols wc*64

  // T2 read-side: byte off in a [R][32]bf16 tile = row*64 + (chunk^((row>>1)&3))*16
  // row = base16 + (lane&15)  ->  xor term is lane-only: (lane>>1)&3
  const int laneoff = (lane & 15) * 64 + (((lane >> 4) ^ ((lane >> 1) & 3)) << 4);
  // T2 stage-side: source column xor, tid-only: row = i*128 + (tid>>2)
  const int scolx = (tid & 3) ^ ((tid >> 3) & 3);
  const int srow = tid >> 2;             // + i*128

  const unsigned short* Ablk = A + (size_t)brow * K_DIM;
  const unsigned short* Bblk = Bm + (size_t)bcol * K_DIM;

  // stage one 16KB tile (2 x global_load_lds dwordx4 per thread)
  auto STAGE_A = [&](int kt) {
    const int k0 = kt * BK, b = kt & 3;
#pragma unroll
    for (int i = 0; i < 2; ++i) {
      int c = i * 512 + tid;
      gl_lds16(Ablk + (size_t)(i * 128 + srow) * K_DIM + k0 + scolx * 8,
               &lds[LDS_A(b) + c * 16]);
    }
  };
  auto STAGE_B = [&](int kt) {
    const int k0 = kt * BK, b = kt & 3;
#pragma unroll
    for (int i = 0; i < 2; ++i) {
      int c = i * 512 + tid;
      gl_lds16(Bblk + (size_t)(i * 128 + srow) * K_DIM + k0 + scolx * 8,
               &lds[LDS_B(b) + c * 16]);
    }
  };

  f32x4 acc[8][4];
#pragma unroll
  for (int i = 0; i < 8; ++i)
#pragma unroll
    for (int j = 0; j < 4; ++j) acc[i][j] = (f32x4){0.f, 0.f, 0.f, 0.f};

  // prologue: tiles 0..2 in flight (12 loads); wait tile 0 (8 outstanding)
  STAGE_A(0); STAGE_B(0);
  STAGE_A(1); STAGE_B(1);
  STAGE_A(2); STAGE_B(2);
  VM_WAIT(8);
  BARRIER();

  for (int kt = 0; kt < NK; ++kt) {
    const int b = kt & 3;
    const int aoff = LDS_A(b) + wr * 8192 + laneoff;   // + mi*1024
    const int boff = LDS_B(b) + wc * 4096 + laneoff;   // + ni*1024
    short8 af[4], bf[4];

    // ---- phase 0: rows [wr*128, +64) x all 64 cols, K=32 ----
#pragma unroll
    for (int ni = 0; ni < 4; ++ni) bf[ni] = *(const short8*)&lds[boff + ni * 1024];
#pragma unroll
    for (int mi = 0; mi < 4; ++mi) af[mi] = *(const short8*)&lds[aoff + mi * 1024];
    if (kt < NK - 3) STAGE_A(kt + 3);   // buf (kt-1)&3: dead since last barrier
    BARRIER();
    __builtin_amdgcn_s_setprio(1);
#pragma unroll
    for (int mi = 0; mi < 4; ++mi)
#pragma unroll
      for (int ni = 0; ni < 4; ++ni)
        acc[mi][ni] = __builtin_amdgcn_mfma_f32_16x16x32_bf16(
            af[mi], bf[ni], acc[mi][ni], 0, 0, 0);
    __builtin_amdgcn_s_setprio(0);
    BARRIER();

    // ---- phase 1: rows [wr*128+64, +64) ----
#pragma unroll
    for (int mi = 0; mi < 4; ++mi) af[mi] = *(const short8*)&lds[aoff + 4096 + mi * 1024];
    if (kt < NK - 3) STAGE_B(kt + 3);
    // counted vmcnt: tile kt+1 must be landed after this wait+barrier.
    // steady state: tiles kt+2,kt+3 in flight (8 loads). epilogue drains 8->4->0.
    if (kt < NK - 3) { VM_WAIT(8); }
    else if (kt == NK - 3) { VM_WAIT(4); }
    else if (kt == NK - 2) { VM_WAIT(0); }
    BARRIER();
    __builtin_amdgcn_s_setprio(1);
#pragma unroll
    for (int mi = 0; mi < 4; ++mi)
#pragma unroll
      for (int ni = 0; ni < 4; ++ni)
        acc[4 + mi][ni] = __builtin_amdgcn_mfma_f32_16x16x32_bf16(
            af[mi], bf[ni], acc[4 + mi][ni], 0, 0, 0);
    __builtin_amdgcn_s_setprio(0);
    BARRIER();
  }

  // epilogue: C/D layout col=lane&15, row=(lane>>4)*4+r  [m89/m91]
  const int crow = brow + wr * 128 + ((lane >> 4) << 2);
  const int ccol = bcol + wc * 64 + (lane & 15);
#pragma unroll
  for (int mi = 0; mi < 8; ++mi)
#pragma unroll
    for (int ni = 0; ni < 4; ++ni) {
      size_t base = (size_t)(crow + mi * 16) * N_DIM + (ccol + ni * 16);
#pragma unroll
      for (int r = 0; r < 4; ++r)
        C[base + (size_t)r * N_DIM] = acc[mi][ni][r];
    }
}

extern "C" void kernel_launch(void* const* d_in, const int* in_sizes, int n_in,
                              void* d_out, int out_size, void* d_ws, size_t ws_size,
                              hipStream_t stream) {
  const float* x     = (const float*)d_in[0];
  const float* signs = (const float*)d_in[1];
  const float* sp    = (const float*)d_in[2];
  const float* sn    = (const float*)d_in[3];
  float* out = (float*)d_out;

  // ws layout: xb (M*K bf16 = 64MiB) | wb (N*K bf16 = 86MiB); total ~150MiB
  unsigned short* xb = (unsigned short*)d_ws;
  unsigned short* wb = xb + (size_t)M_DIM * K_DIM;

  cvt_x_kernel<<<(M_DIM * K_DIM / 8) / 256, 256, 0, stream>>>(x, xb);
  dequant_w_kernel<<<((size_t)N_DIM * K_DIM / 8) / 256, 256, 0, stream>>>(signs, sp, sn, wb);
  gemm_kernel<<<NWG, 512, 0, stream>>>(xb, wb, out);
}